// Round 13
// baseline (330.748 us; speedup 1.0000x reference)
//
#include <hip/hip_runtime.h>
#include <hip/hip_fp16.h>
#include <math.h>

#define NEG_SLOPE 0.2f

__device__ __forceinline__ float lrelu(float v) { return v > 0.0f ? v : NEG_SLOPE * v; }

typedef _Float16 half8 __attribute__((ext_vector_type(8)));
typedef float floatx4 __attribute__((ext_vector_type(4)));

// ---------------- CSR build ----------------

// XCD-windowed count (windows disjoint; correctness independent of XCD mapping).
__global__ __launch_bounds__(256) void count_win_k(const int* __restrict__ dst,
                                                   int* __restrict__ counts,
                                                   int e, int winSize) {
  const int win = blockIdx.x & 7;
  const int lo = win * winSize;
  const int hi = lo + winSize;
  const int base = (blockIdx.x >> 3) * 4096 + threadIdx.x;
  for (int t = 0; t < 16; ++t) {
    int i = base + t * 256;
    if (i < e) {
      int d = dst[i];
      if (d >= lo && d < hi) atomicAdd(&counts[d], 1);
    }
  }
}

__global__ __launch_bounds__(256) void block_sum_k(const int* __restrict__ counts,
                                                   int* __restrict__ blockSums, int n) {
  int i = blockIdx.x * 256 + threadIdx.x;
  int v = (i < n) ? counts[i] : 0;
  for (int o = 32; o > 0; o >>= 1) v += __shfl_xor(v, o);
  __shared__ int ws[4];
  if ((threadIdx.x & 63) == 0) ws[threadIdx.x >> 6] = v;
  __syncthreads();
  if (threadIdx.x == 0) blockSums[blockIdx.x] = ws[0] + ws[1] + ws[2] + ws[3];
}

__global__ __launch_bounds__(256) void scan_sums_k(int* __restrict__ blockSums, int nb,
                                                   int* __restrict__ total_out) {
  __shared__ int sh[256];
  const int tid = threadIdx.x;
  int run = 0;
  for (int base = 0; base < nb; base += 256) {
    int i = base + tid;
    int v = (i < nb) ? blockSums[i] : 0;
    sh[tid] = v;
    __syncthreads();
    for (int o = 1; o < 256; o <<= 1) {
      int t = (tid >= o) ? sh[tid - o] : 0;
      __syncthreads();
      sh[tid] += t;
      __syncthreads();
    }
    int chunkTotal = sh[255];
    if (i < nb) blockSums[i] = run + sh[tid] - v;
    __syncthreads();
    run += chunkTotal;
  }
  if (tid == 0) *total_out = run;
}

__global__ __launch_bounds__(256) void scan_apply_k(int* __restrict__ counts_cursor,
                                                    const int* __restrict__ blockOffs,
                                                    int* __restrict__ row_ptr, int n) {
  __shared__ int sh[256];
  const int tid = threadIdx.x;
  const int i = blockIdx.x * 256 + tid;
  int v = (i < n) ? counts_cursor[i] : 0;
  sh[tid] = v;
  __syncthreads();
  for (int o = 1; o < 256; o <<= 1) {
    int t = (tid >= o) ? sh[tid - o] : 0;
    __syncthreads();
    sh[tid] += t;
    __syncthreads();
  }
  if (i < n) {
    int excl = blockOffs[blockIdx.x] + sh[tid] - v;
    row_ptr[i] = excl;
    counts_cursor[i] = excl;
  }
}

__global__ __launch_bounds__(256) void scatter_win_k(const int* __restrict__ src,
                                                     const int* __restrict__ dst,
                                                     int* __restrict__ cursor,
                                                     int* __restrict__ csr,
                                                     int e, int winSize) {
  const int win = blockIdx.x & 7;
  const int lo = win * winSize;
  const int hi = lo + winSize;
  const int base = (blockIdx.x >> 3) * 4096 + threadIdx.x;
  for (int t = 0; t < 16; ++t) {
    int i = base + t * 256;
    if (i < e) {
      int d = dst[i];
      if (d >= lo && d < hi) {
        int pos = atomicAdd(&cursor[d], 1);
        csr[pos] = src[i];
      }
    }
  }
}

// ---------------- dtype converts (once per launch) ----------------

__global__ __launch_bounds__(256) void cvt_f2h_k(const float* __restrict__ src,
                                                 __half* __restrict__ dst, int count4) {
  int i = blockIdx.x * 256 + threadIdx.x;
  if (i < count4) {
    float4 v = ((const float4*)src)[i];
    __half2 a = __floats2half2_rn(v.x, v.y);
    __half2 b = __floats2half2_rn(v.z, v.w);
    uint2 pk;
    pk.x = *(unsigned int*)&a;
    pk.y = *(unsigned int*)&b;
    ((uint2*)dst)[i] = pk;
  }
}

__global__ __launch_bounds__(256) void cvt_wt3_k(const float* __restrict__ W0,
                                                 const float* __restrict__ W1,
                                                 const float* __restrict__ W2,
                                                 __half* __restrict__ Wt0,
                                                 __half* __restrict__ Wt1,
                                                 __half* __restrict__ Wt2) {
  int i = blockIdx.x * 256 + threadIdx.x;
  if (i < 128 * 128) {
    int col = i >> 7, k = i & 127;
    Wt0[i] = __float2half(W0[k * 128 + col]);
    Wt1[i] = __float2half(W1[k * 128 + col]);
    if (col < 64) Wt2[(size_t)col * 128 + k] = __float2half(W2[k * 64 + col]);
  }
}

// ---------------- MFMA GEMM + fused attention dots ----------------

template<int M, int H_>
__global__ __launch_bounds__(256) void gemm_attn_mfma_k(const __half* __restrict__ Xh,
                                                        const __half* __restrict__ Wt,
                                                        const float* __restrict__ a_src,
                                                        const float* __restrict__ a_dst,
                                                        __half* __restrict__ Yh,
                                                        float* __restrict__ sArr,
                                                        float* __restrict__ dArr, int n) {
  constexpr int CT = M / 16;
  constexpr int LP = 136;  // LDS row pitch in halves (272B: 2-way conflict = free)
  __shared__ _Float16 Xs[64 * LP];
  __shared__ _Float16 Ws[M * LP];
  const int tid = threadIdx.x;
  const int w = tid >> 6;
  const int lane = tid & 63;
  const int l15 = lane & 15;
  const int quad = lane >> 4;
  const int rb = blockIdx.x * 64;

  for (int t = 0; t < 4; ++t) {
    int idx = tid + t * 256;
    int r = idx >> 4, c8 = idx & 15;
    uint4 v = make_uint4(0, 0, 0, 0);
    if (rb + r < n) v = *(const uint4*)(Xh + (size_t)(rb + r) * 128 + c8 * 8);
    *(uint4*)&Xs[r * LP + c8 * 8] = v;
  }
  for (int t = 0; t < CT; ++t) {
    int idx = tid + t * 256;
    int r = idx >> 4, c8 = idx & 15;
    *(uint4*)&Ws[r * LP + c8 * 8] = *(const uint4*)(Wt + (size_t)r * 128 + c8 * 8);
  }
  __syncthreads();

  floatx4 acc[CT];
  for (int c = 0; c < CT; ++c)
    for (int j = 0; j < 4; ++j) acc[c][j] = 0.f;

  const int arow = w * 16 + l15;
  for (int kq = 0; kq < 4; ++kq) {
    half8 a = *(const half8*)&Xs[arow * LP + kq * 32 + quad * 8];
    for (int c = 0; c < CT; ++c) {
      half8 b = *(const half8*)&Ws[(c * 16 + l15) * LP + kq * 32 + quad * 8];
      acc[c] = __builtin_amdgcn_mfma_f32_16x16x32_f16(a, b, acc[c], 0, 0, 0);
    }
  }

  float as[CT], ad[CT];
  for (int c = 0; c < CT; ++c) {
    as[c] = a_src[c * 16 + l15];
    ad[c] = a_dst[c * 16 + l15];
  }

  for (int c = 0; c < CT; ++c) {
    for (int r = 0; r < 4; ++r) {
      int row = rb + w * 16 + quad * 4 + r;
      if (row < n) Yh[(size_t)row * M + c * 16 + l15] = __float2half(acc[c][r]);
    }
  }

  for (int r = 0; r < 4; ++r) {
    int row = rb + w * 16 + quad * 4 + r;
    float s0 = 0.f, d0 = 0.f, s1 = 0.f, d1 = 0.f;
    if (H_ == 2) {
      for (int c = 0; c < CT / 2; ++c) {
        s0 += acc[c][r] * as[c];
        d0 += acc[c][r] * ad[c];
      }
      for (int c = CT / 2; c < CT; ++c) {
        s1 += acc[c][r] * as[c];
        d1 += acc[c][r] * ad[c];
      }
    } else {
      for (int c = 0; c < CT; ++c) {
        s0 += acc[c][r] * as[c];
        d0 += acc[c][r] * ad[c];
      }
    }
    for (int o = 1; o < 16; o <<= 1) {
      s0 += __shfl_xor(s0, o);
      d0 += __shfl_xor(d0, o);
      if (H_ == 2) {
        s1 += __shfl_xor(s1, o);
        d1 += __shfl_xor(d1, o);
      }
    }
    if (l15 == 0 && row < n) {
      if (H_ == 2) {
        sArr[row * 2] = s0;
        sArr[row * 2 + 1] = s1;
        dArr[row * 2] = d0;
        dArr[row * 2 + 1] = d1;
      } else {
        sArr[row] = s0;
        dArr[row] = d0;
      }
    }
  }
}

// ---------------- aggregation: TWO nodes per wave, 32 lanes each, unroll 8 ----------
// fp16 H=2 row = 256 B = 32 lanes x uint2(8B). Unroll 8 keeps 8 gather loads
// (16 edges) in flight per wave. Self-loop loads issued before the edge loop.

__global__ __launch_bounds__(256) void edge2h_k(const __half* __restrict__ xlh,
                                                const float* __restrict__ sArr,
                                                const float* __restrict__ dArr,
                                                const float* __restrict__ bias,
                                                const int* __restrict__ row_ptr,
                                                const int* __restrict__ csr,
                                                __half* __restrict__ outh, int n) {
  const int wid = threadIdx.x >> 6;
  const int lane = threadIdx.x & 63;
  const int sub = lane >> 5;
  const int l32 = lane & 31;
  const int node = blockIdx.x * 8 + wid * 2 + sub;
  if (node >= n) return;
  const int row = row_ptr[node];
  const int deg = row_ptr[node + 1] - row;
  const int head = l32 >> 4;
  const uint2* __restrict__ xq = (const uint2*)xlh;
  const float2 dn2 = ((const float2*)dArr)[node];
  const float dnsel = head ? dn2.y : dn2.x;

  // self-loop loads early (overlap with first edge batch)
  float svS = sArr[node * 2 + head];
  uint2 pS = xq[(size_t)node * 32 + l32];

  float a0 = 0.f, a1 = 0.f, a2 = 0.f, a3 = 0.f;
  float den = 0.f;
  int j = 0;
  for (; j + 8 <= deg; j += 8) {
    int idx[8];
    float sv[8];
    uint2 p[8];
    for (int t = 0; t < 8; ++t) idx[t] = csr[row + j + t];
    for (int t = 0; t < 8; ++t) sv[t] = sArr[idx[t] * 2 + head];
    for (int t = 0; t < 8; ++t) p[t] = xq[(size_t)idx[t] * 32 + l32];
    for (int t = 0; t < 8; ++t) {
      float w = __expf(lrelu(sv[t] + dnsel));
      den += w;
      float2 v0 = __half22float2(*(__half2*)&p[t].x);
      float2 v1 = __half22float2(*(__half2*)&p[t].y);
      a0 += w * v0.x; a1 += w * v0.y; a2 += w * v1.x; a3 += w * v1.y;
    }
  }
  for (; j < deg; ++j) {
    int i0 = csr[row + j];
    float sv = sArr[i0 * 2 + head];
    uint2 p = xq[(size_t)i0 * 32 + l32];
    float w = __expf(lrelu(sv + dnsel));
    den += w;
    float2 v0 = __half22float2(*(__half2*)&p.x);
    float2 v1 = __half22float2(*(__half2*)&p.y);
    a0 += w * v0.x; a1 += w * v0.y; a2 += w * v1.x; a3 += w * v1.y;
  }
  // self loop
  float wS = __expf(lrelu(svS + dnsel));
  den += wS;
  {
    float2 v0 = __half22float2(*(__half2*)&pS.x);
    float2 v1 = __half22float2(*(__half2*)&pS.y);
    a0 += wS * v0.x; a1 += wS * v0.y; a2 += wS * v1.x; a3 += wS * v1.y;
  }

  float wi = 1.f / den;
  float4 bb = ((const float4*)bias)[l32];
  float r0 = a0 * wi + bb.x;
  float r1 = a1 * wi + bb.y;
  float r2 = a2 * wi + bb.z;
  float r3 = a3 * wi + bb.w;
  r0 = r0 > 0.f ? r0 : expm1f(r0);
  r1 = r1 > 0.f ? r1 : expm1f(r1);
  r2 = r2 > 0.f ? r2 : expm1f(r2);
  r3 = r3 > 0.f ? r3 : expm1f(r3);
  __half2 h0 = __floats2half2_rn(r0, r1);
  __half2 h1 = __floats2half2_rn(r2, r3);
  uint2 pk;
  pk.x = *(unsigned int*)&h0;
  pk.y = *(unsigned int*)&h1;
  ((uint2*)outh)[(size_t)node * 32 + l32] = pk;
}

// H=1: row = 128 B = 32 lanes x half2(4B); fp32 output (float2/lane).
__global__ __launch_bounds__(256) void edge1h_k(const __half* __restrict__ xlh,
                                                const float* __restrict__ sArr,
                                                const float* __restrict__ dArr,
                                                const float* __restrict__ bias,
                                                const int* __restrict__ row_ptr,
                                                const int* __restrict__ csr,
                                                float* __restrict__ outp, int n) {
  const int wid = threadIdx.x >> 6;
  const int lane = threadIdx.x & 63;
  const int sub = lane >> 5;
  const int l32 = lane & 31;
  const int node = blockIdx.x * 8 + wid * 2 + sub;
  if (node >= n) return;
  const int row = row_ptr[node];
  const int deg = row_ptr[node + 1] - row;
  const unsigned int* __restrict__ xq = (const unsigned int*)xlh;
  const float dn = dArr[node];

  float svS = sArr[node];
  unsigned int pS = xq[(size_t)node * 32 + l32];

  float a0 = 0.f, a1 = 0.f;
  float den = 0.f;
  int j = 0;
  for (; j + 8 <= deg; j += 8) {
    int idx[8];
    float sv[8];
    unsigned int p[8];
    for (int t = 0; t < 8; ++t) idx[t] = csr[row + j + t];
    for (int t = 0; t < 8; ++t) sv[t] = sArr[idx[t]];
    for (int t = 0; t < 8; ++t) p[t] = xq[(size_t)idx[t] * 32 + l32];
    for (int t = 0; t < 8; ++t) {
      float w = __expf(lrelu(sv[t] + dn));
      den += w;
      float2 v = __half22float2(*(__half2*)&p[t]);
      a0 += w * v.x; a1 += w * v.y;
    }
  }
  for (; j < deg; ++j) {
    int i0 = csr[row + j];
    float sv = sArr[i0];
    unsigned int p = xq[(size_t)i0 * 32 + l32];
    float w = __expf(lrelu(sv + dn));
    den += w;
    float2 v = __half22float2(*(__half2*)&p);
    a0 += w * v.x; a1 += w * v.y;
  }
  float wS = __expf(lrelu(svS + dn));
  den += wS;
  {
    float2 v = __half22float2(*(__half2*)&pS);
    a0 += wS * v.x; a1 += wS * v.y;
  }

  float wi = 1.f / den;
  float2 bb = ((const float2*)bias)[l32];
  ((float2*)outp)[(size_t)node * 32 + l32] =
      make_float2(a0 * wi + bb.x, a1 * wi + bb.y);
}

// ---------------- launch ----------------

extern "C" void kernel_launch(void* const* d_in, const int* in_sizes, int n_in,
                              void* d_out, int out_size, void* d_ws, size_t ws_size,
                              hipStream_t stream) {
  const float* x  = (const float*)d_in[0];
  const int* ei   = (const int*)d_in[1];
  const float* W0 = (const float*)d_in[2];
  const float* as0 = (const float*)d_in[3];
  const float* ad0 = (const float*)d_in[4];
  const float* b0 = (const float*)d_in[5];
  const float* W1 = (const float*)d_in[6];
  const float* as1 = (const float*)d_in[7];
  const float* ad1 = (const float*)d_in[8];
  const float* b1 = (const float*)d_in[9];
  const float* W2 = (const float*)d_in[10];
  const float* as2 = (const float*)d_in[11];
  const float* ad2 = (const float*)d_in[12];
  const float* b2 = (const float*)d_in[13];
  float* out = (float*)d_out;

  const int n = in_sizes[0] / 128;
  const int e = in_sizes[1] / 2;
  const int* srcIdx = ei;
  const int* dstIdx = ei + e;

  float* ws = (float*)d_ws;
  float* sArr = ws;                                  // n*2
  float* dArr = sArr + (size_t)n * 2;                // n*2
  __half* xlh = (__half*)(dArr + (size_t)n * 2);     // n*128 halves
  __half* bufHh = xlh + (size_t)n * 128;             // n*128 halves
  __half* Wt0 = bufHh + (size_t)n * 128;             // 128*128
  __half* Wt1 = Wt0 + 128 * 128;                     // 128*128
  __half* Wt2 = Wt1 + 128 * 128;                     // 64*128
  int* csr = (int*)(Wt2 + 64 * 128);                 // e
  int* row_ptr = csr + e;                            // n+1
  int* cursor = row_ptr + (n + 1);                   // n
  int* blockSums = cursor + n;                       // nb

  const int nb = (n + 255) / 256;
  const int winSize = (n + 7) / 8;
  const int gwin = 8 * ((e + 4095) / 4096);

  cvt_wt3_k<<<(128 * 128 + 255) / 256, 256, 0, stream>>>(W0, W1, W2, Wt0, Wt1, Wt2);
  cvt_f2h_k<<<((n * 32) + 255) / 256, 256, 0, stream>>>(x, bufHh, n * 32);

  hipMemsetAsync(cursor, 0, (size_t)n * sizeof(int), stream);
  count_win_k<<<gwin, 256, 0, stream>>>(dstIdx, cursor, e, winSize);
  block_sum_k<<<nb, 256, 0, stream>>>(cursor, blockSums, n);
  scan_sums_k<<<1, 256, 0, stream>>>(blockSums, nb, row_ptr + n);
  scan_apply_k<<<nb, 256, 0, stream>>>(cursor, blockSums, row_ptr, n);
  scatter_win_k<<<gwin, 256, 0, stream>>>(srcIdx, dstIdx, cursor, csr, e, winSize);

  const int gb = (n + 63) / 64;
  const int gp = (n + 7) / 8;  // pair kernels: 8 nodes/block (4 waves x 2)

  // layer 0
  gemm_attn_mfma_k<128, 2><<<gb, 256, 0, stream>>>(bufHh, Wt0, as0, ad0, xlh, sArr, dArr, n);
  edge2h_k<<<gp, 256, 0, stream>>>(xlh, sArr, dArr, b0, row_ptr, csr, bufHh, n);

  // layer 1
  gemm_attn_mfma_k<128, 2><<<gb, 256, 0, stream>>>(bufHh, Wt1, as1, ad1, xlh, sArr, dArr, n);
  edge2h_k<<<gp, 256, 0, stream>>>(xlh, sArr, dArr, b1, row_ptr, csr, bufHh, n);

  // layer 2 (H=1, no concat, no elu, fp32 out)
  gemm_attn_mfma_k<64, 1><<<gb, 256, 0, stream>>>(bufHh, Wt2, as2, ad2, xlh, sArr, dArr, n);
  edge1h_k<<<gp, 256, 0, stream>>>(xlh, sArr, dArr, b2, row_ptr, csr, out, n);
}

// Round 14
// 316.281 us; speedup vs baseline: 1.0457x; 1.0457x over previous
//
#include <hip/hip_runtime.h>
#include <hip/hip_fp16.h>
#include <math.h>

#define NEG_SLOPE 0.2f

__device__ __forceinline__ float lrelu(float v) { return v > 0.0f ? v : NEG_SLOPE * v; }

typedef _Float16 half8 __attribute__((ext_vector_type(8)));
typedef float floatx4 __attribute__((ext_vector_type(4)));

// ---------------- CSR build ----------------

// XCD-windowed count (windows disjoint; correctness independent of XCD mapping).
__global__ __launch_bounds__(256) void count_win_k(const int* __restrict__ dst,
                                                   int* __restrict__ counts,
                                                   int e, int winSize) {
  const int win = blockIdx.x & 7;
  const int lo = win * winSize;
  const int hi = lo + winSize;
  const int base = (blockIdx.x >> 3) * 4096 + threadIdx.x;
  for (int t = 0; t < 16; ++t) {
    int i = base + t * 256;
    if (i < e) {
      int d = dst[i];
      if (d >= lo && d < hi) atomicAdd(&counts[d], 1);
    }
  }
}

__global__ __launch_bounds__(256) void block_sum_k(const int* __restrict__ counts,
                                                   int* __restrict__ blockSums, int n) {
  int i = blockIdx.x * 256 + threadIdx.x;
  int v = (i < n) ? counts[i] : 0;
  for (int o = 32; o > 0; o >>= 1) v += __shfl_xor(v, o);
  __shared__ int ws[4];
  if ((threadIdx.x & 63) == 0) ws[threadIdx.x >> 6] = v;
  __syncthreads();
  if (threadIdx.x == 0) blockSums[blockIdx.x] = ws[0] + ws[1] + ws[2] + ws[3];
}

__global__ __launch_bounds__(256) void scan_sums_k(int* __restrict__ blockSums, int nb,
                                                   int* __restrict__ total_out) {
  __shared__ int sh[256];
  const int tid = threadIdx.x;
  int run = 0;
  for (int base = 0; base < nb; base += 256) {
    int i = base + tid;
    int v = (i < nb) ? blockSums[i] : 0;
    sh[tid] = v;
    __syncthreads();
    for (int o = 1; o < 256; o <<= 1) {
      int t = (tid >= o) ? sh[tid - o] : 0;
      __syncthreads();
      sh[tid] += t;
      __syncthreads();
    }
    int chunkTotal = sh[255];
    if (i < nb) blockSums[i] = run + sh[tid] - v;
    __syncthreads();
    run += chunkTotal;
  }
  if (tid == 0) *total_out = run;
}

__global__ __launch_bounds__(256) void scan_apply_k(int* __restrict__ counts_cursor,
                                                    const int* __restrict__ blockOffs,
                                                    int* __restrict__ row_ptr, int n) {
  __shared__ int sh[256];
  const int tid = threadIdx.x;
  const int i = blockIdx.x * 256 + tid;
  int v = (i < n) ? counts_cursor[i] : 0;
  sh[tid] = v;
  __syncthreads();
  for (int o = 1; o < 256; o <<= 1) {
    int t = (tid >= o) ? sh[tid - o] : 0;
    __syncthreads();
    sh[tid] += t;
    __syncthreads();
  }
  if (i < n) {
    int excl = blockOffs[blockIdx.x] + sh[tid] - v;
    row_ptr[i] = excl;
    counts_cursor[i] = excl;
  }
}

__global__ __launch_bounds__(256) void scatter_win_k(const int* __restrict__ src,
                                                     const int* __restrict__ dst,
                                                     int* __restrict__ cursor,
                                                     int* __restrict__ csr,
                                                     int e, int winSize) {
  const int win = blockIdx.x & 7;
  const int lo = win * winSize;
  const int hi = lo + winSize;
  const int base = (blockIdx.x >> 3) * 4096 + threadIdx.x;
  for (int t = 0; t < 16; ++t) {
    int i = base + t * 256;
    if (i < e) {
      int d = dst[i];
      if (d >= lo && d < hi) {
        int pos = atomicAdd(&cursor[d], 1);
        csr[pos] = src[i];
      }
    }
  }
}

// ---------------- weight converts (once per launch) ----------------

__global__ __launch_bounds__(256) void cvt_wt3_k(const float* __restrict__ W0,
                                                 const float* __restrict__ W1,
                                                 const float* __restrict__ W2,
                                                 __half* __restrict__ Wt0,
                                                 __half* __restrict__ Wt1,
                                                 __half* __restrict__ Wt2) {
  int i = blockIdx.x * 256 + threadIdx.x;
  if (i < 128 * 128) {
    int col = i >> 7, k = i & 127;
    Wt0[i] = __float2half(W0[k * 128 + col]);
    Wt1[i] = __float2half(W1[k * 128 + col]);
    if (col < 64) Wt2[(size_t)col * 128 + k] = __float2half(W2[k * 64 + col]);
  }
}

// ---------------- MFMA GEMM + fused attention dots ----------------
// Input templated: fp16 rows (uint4 stage) or fp32 rows (float4 x2, convert
// during staging -- fuses the x fp32->fp16 cast into layer 0).

template<int M, int H_, bool IN_F32>
__global__ __launch_bounds__(256) void gemm_attn_mfma_k(const void* __restrict__ Xin,
                                                        const __half* __restrict__ Wt,
                                                        const float* __restrict__ a_src,
                                                        const float* __restrict__ a_dst,
                                                        __half* __restrict__ Yh,
                                                        float* __restrict__ sArr,
                                                        float* __restrict__ dArr, int n) {
  constexpr int CT = M / 16;
  constexpr int LP = 136;  // LDS row pitch in halves (272B: 2-way conflict = free)
  __shared__ _Float16 Xs[64 * LP];
  __shared__ _Float16 Ws[M * LP];
  const int tid = threadIdx.x;
  const int w = tid >> 6;
  const int lane = tid & 63;
  const int l15 = lane & 15;
  const int quad = lane >> 4;
  const int rb = blockIdx.x * 64;

  if (IN_F32) {
    const float* Xf = (const float*)Xin;
    for (int t = 0; t < 8; ++t) {
      int idx = tid + t * 256;         // 64 rows x 32 float4-groups
      int r = idx >> 5, c4 = idx & 31;
      float4 v = make_float4(0.f, 0.f, 0.f, 0.f);
      if (rb + r < n) v = *(const float4*)(Xf + (size_t)(rb + r) * 128 + c4 * 4);
      __half2 a = __floats2half2_rn(v.x, v.y);
      __half2 b = __floats2half2_rn(v.z, v.w);
      uint2 pk;
      pk.x = *(unsigned int*)&a;
      pk.y = *(unsigned int*)&b;
      *(uint2*)&Xs[r * LP + c4 * 4] = pk;
    }
  } else {
    const __half* Xh = (const __half*)Xin;
    for (int t = 0; t < 4; ++t) {
      int idx = tid + t * 256;         // 64 rows x 16 groups of 8 halves
      int r = idx >> 4, c8 = idx & 15;
      uint4 v = make_uint4(0, 0, 0, 0);
      if (rb + r < n) v = *(const uint4*)(Xh + (size_t)(rb + r) * 128 + c8 * 8);
      *(uint4*)&Xs[r * LP + c8 * 8] = v;
    }
  }
  for (int t = 0; t < CT; ++t) {
    int idx = tid + t * 256;
    int r = idx >> 4, c8 = idx & 15;
    *(uint4*)&Ws[r * LP + c8 * 8] = *(const uint4*)(Wt + (size_t)r * 128 + c8 * 8);
  }
  __syncthreads();

  floatx4 acc[CT];
  for (int c = 0; c < CT; ++c)
    for (int j = 0; j < 4; ++j) acc[c][j] = 0.f;

  const int arow = w * 16 + l15;
  for (int kq = 0; kq < 4; ++kq) {
    half8 a = *(const half8*)&Xs[arow * LP + kq * 32 + quad * 8];
    for (int c = 0; c < CT; ++c) {
      half8 b = *(const half8*)&Ws[(c * 16 + l15) * LP + kq * 32 + quad * 8];
      acc[c] = __builtin_amdgcn_mfma_f32_16x16x32_f16(a, b, acc[c], 0, 0, 0);
    }
  }

  float as[CT], ad[CT];
  for (int c = 0; c < CT; ++c) {
    as[c] = a_src[c * 16 + l15];
    ad[c] = a_dst[c * 16 + l15];
  }

  for (int c = 0; c < CT; ++c) {
    for (int r = 0; r < 4; ++r) {
      int row = rb + w * 16 + quad * 4 + r;
      if (row < n) Yh[(size_t)row * M + c * 16 + l15] = __float2half(acc[c][r]);
    }
  }

  for (int r = 0; r < 4; ++r) {
    int row = rb + w * 16 + quad * 4 + r;
    float s0 = 0.f, d0 = 0.f, s1 = 0.f, d1 = 0.f;
    if (H_ == 2) {
      for (int c = 0; c < CT / 2; ++c) {
        s0 += acc[c][r] * as[c];
        d0 += acc[c][r] * ad[c];
      }
      for (int c = CT / 2; c < CT; ++c) {
        s1 += acc[c][r] * as[c];
        d1 += acc[c][r] * ad[c];
      }
    } else {
      for (int c = 0; c < CT; ++c) {
        s0 += acc[c][r] * as[c];
        d0 += acc[c][r] * ad[c];
      }
    }
    for (int o = 1; o < 16; o <<= 1) {
      s0 += __shfl_xor(s0, o);
      d0 += __shfl_xor(d0, o);
      if (H_ == 2) {
        s1 += __shfl_xor(s1, o);
        d1 += __shfl_xor(d1, o);
      }
    }
    if (l15 == 0 && row < n) {
      if (H_ == 2) {
        sArr[row * 2] = s0;
        sArr[row * 2 + 1] = s1;
        dArr[row * 2] = d0;
        dArr[row * 2 + 1] = d1;
      } else {
        sArr[row] = s0;
        dArr[row] = d0;
      }
    }
  }
}

// ---------------- aggregation: TWO nodes per wave, 32 lanes each, unroll 4 ----------
// (unroll 8 regressed: mean degree ~17 pushes work into the serial tail)

__global__ __launch_bounds__(256) void edge2h_k(const __half* __restrict__ xlh,
                                                const float* __restrict__ sArr,
                                                const float* __restrict__ dArr,
                                                const float* __restrict__ bias,
                                                const int* __restrict__ row_ptr,
                                                const int* __restrict__ csr,
                                                __half* __restrict__ outh, int n) {
  const int wid = threadIdx.x >> 6;
  const int lane = threadIdx.x & 63;
  const int sub = lane >> 5;
  const int l32 = lane & 31;
  const int node = blockIdx.x * 8 + wid * 2 + sub;
  if (node >= n) return;
  const int row = row_ptr[node];
  const int deg = row_ptr[node + 1] - row;
  const int head = l32 >> 4;
  const uint2* __restrict__ xq = (const uint2*)xlh;
  const float2 dn2 = ((const float2*)dArr)[node];
  const float dnsel = head ? dn2.y : dn2.x;

  // self-loop loads early (overlap with first edge batch)
  float svS = sArr[node * 2 + head];
  uint2 pS = xq[(size_t)node * 32 + l32];

  float a0 = 0.f, a1 = 0.f, a2 = 0.f, a3 = 0.f;
  float den = 0.f;
  int j = 0;
  for (; j + 4 <= deg; j += 4) {
    int idx[4];
    float sv[4];
    uint2 p[4];
    for (int t = 0; t < 4; ++t) idx[t] = csr[row + j + t];
    for (int t = 0; t < 4; ++t) sv[t] = sArr[idx[t] * 2 + head];
    for (int t = 0; t < 4; ++t) p[t] = xq[(size_t)idx[t] * 32 + l32];
    for (int t = 0; t < 4; ++t) {
      float w = __expf(lrelu(sv[t] + dnsel));
      den += w;
      float2 v0 = __half22float2(*(__half2*)&p[t].x);
      float2 v1 = __half22float2(*(__half2*)&p[t].y);
      a0 += w * v0.x; a1 += w * v0.y; a2 += w * v1.x; a3 += w * v1.y;
    }
  }
  for (; j < deg; ++j) {
    int i0 = csr[row + j];
    float sv = sArr[i0 * 2 + head];
    uint2 p = xq[(size_t)i0 * 32 + l32];
    float w = __expf(lrelu(sv + dnsel));
    den += w;
    float2 v0 = __half22float2(*(__half2*)&p.x);
    float2 v1 = __half22float2(*(__half2*)&p.y);
    a0 += w * v0.x; a1 += w * v0.y; a2 += w * v1.x; a3 += w * v1.y;
  }
  // self loop
  float wS = __expf(lrelu(svS + dnsel));
  den += wS;
  {
    float2 v0 = __half22float2(*(__half2*)&pS.x);
    float2 v1 = __half22float2(*(__half2*)&pS.y);
    a0 += wS * v0.x; a1 += wS * v0.y; a2 += wS * v1.x; a3 += wS * v1.y;
  }

  float wi = 1.f / den;
  float4 bb = ((const float4*)bias)[l32];
  float r0 = a0 * wi + bb.x;
  float r1 = a1 * wi + bb.y;
  float r2 = a2 * wi + bb.z;
  float r3 = a3 * wi + bb.w;
  r0 = r0 > 0.f ? r0 : expm1f(r0);
  r1 = r1 > 0.f ? r1 : expm1f(r1);
  r2 = r2 > 0.f ? r2 : expm1f(r2);
  r3 = r3 > 0.f ? r3 : expm1f(r3);
  __half2 h0 = __floats2half2_rn(r0, r1);
  __half2 h1 = __floats2half2_rn(r2, r3);
  uint2 pk;
  pk.x = *(unsigned int*)&h0;
  pk.y = *(unsigned int*)&h1;
  ((uint2*)outh)[(size_t)node * 32 + l32] = pk;
}

// H=1: row = 128 B = 32 lanes x half2(4B); fp32 output (float2/lane).
__global__ __launch_bounds__(256) void edge1h_k(const __half* __restrict__ xlh,
                                                const float* __restrict__ sArr,
                                                const float* __restrict__ dArr,
                                                const float* __restrict__ bias,
                                                const int* __restrict__ row_ptr,
                                                const int* __restrict__ csr,
                                                float* __restrict__ outp, int n) {
  const int wid = threadIdx.x >> 6;
  const int lane = threadIdx.x & 63;
  const int sub = lane >> 5;
  const int l32 = lane & 31;
  const int node = blockIdx.x * 8 + wid * 2 + sub;
  if (node >= n) return;
  const int row = row_ptr[node];
  const int deg = row_ptr[node + 1] - row;
  const unsigned int* __restrict__ xq = (const unsigned int*)xlh;
  const float dn = dArr[node];

  float svS = sArr[node];
  unsigned int pS = xq[(size_t)node * 32 + l32];

  float a0 = 0.f, a1 = 0.f;
  float den = 0.f;
  int j = 0;
  for (; j + 4 <= deg; j += 4) {
    int idx[4];
    float sv[4];
    unsigned int p[4];
    for (int t = 0; t < 4; ++t) idx[t] = csr[row + j + t];
    for (int t = 0; t < 4; ++t) sv[t] = sArr[idx[t]];
    for (int t = 0; t < 4; ++t) p[t] = xq[(size_t)idx[t] * 32 + l32];
    for (int t = 0; t < 4; ++t) {
      float w = __expf(lrelu(sv[t] + dn));
      den += w;
      float2 v = __half22float2(*(__half2*)&p[t]);
      a0 += w * v.x; a1 += w * v.y;
    }
  }
  for (; j < deg; ++j) {
    int i0 = csr[row + j];
    float sv = sArr[i0];
    unsigned int p = xq[(size_t)i0 * 32 + l32];
    float w = __expf(lrelu(sv + dn));
    den += w;
    float2 v = __half22float2(*(__half2*)&p);
    a0 += w * v.x; a1 += w * v.y;
  }
  float wS = __expf(lrelu(svS + dn));
  den += wS;
  {
    float2 v = __half22float2(*(__half2*)&pS);
    a0 += wS * v.x; a1 += wS * v.y;
  }

  float wi = 1.f / den;
  float2 bb = ((const float2*)bias)[l32];
  ((float2*)outp)[(size_t)node * 32 + l32] =
      make_float2(a0 * wi + bb.x, a1 * wi + bb.y);
}

// ---------------- launch ----------------

extern "C" void kernel_launch(void* const* d_in, const int* in_sizes, int n_in,
                              void* d_out, int out_size, void* d_ws, size_t ws_size,
                              hipStream_t stream) {
  const float* x  = (const float*)d_in[0];
  const int* ei   = (const int*)d_in[1];
  const float* W0 = (const float*)d_in[2];
  const float* as0 = (const float*)d_in[3];
  const float* ad0 = (const float*)d_in[4];
  const float* b0 = (const float*)d_in[5];
  const float* W1 = (const float*)d_in[6];
  const float* as1 = (const float*)d_in[7];
  const float* ad1 = (const float*)d_in[8];
  const float* b1 = (const float*)d_in[9];
  const float* W2 = (const float*)d_in[10];
  const float* as2 = (const float*)d_in[11];
  const float* ad2 = (const float*)d_in[12];
  const float* b2 = (const float*)d_in[13];
  float* out = (float*)d_out;

  const int n = in_sizes[0] / 128;
  const int e = in_sizes[1] / 2;
  const int* srcIdx = ei;
  const int* dstIdx = ei + e;

  float* ws = (float*)d_ws;
  float* sArr = ws;                                  // n*2
  float* dArr = sArr + (size_t)n * 2;                // n*2
  __half* xlh = (__half*)(dArr + (size_t)n * 2);     // n*128 halves
  __half* bufHh = xlh + (size_t)n * 128;             // n*128 halves
  __half* Wt0 = bufHh + (size_t)n * 128;             // 128*128
  __half* Wt1 = Wt0 + 128 * 128;                     // 128*128
  __half* Wt2 = Wt1 + 128 * 128;                     // 64*128
  int* csr = (int*)(Wt2 + 64 * 128);                 // e
  int* row_ptr = csr + e;                            // n+1
  int* cursor = row_ptr + (n + 1);                   // n
  int* blockSums = cursor + n;                       // nb

  const int nb = (n + 255) / 256;
  const int winSize = (n + 7) / 8;
  const int gwin = 8 * ((e + 4095) / 4096);

  cvt_wt3_k<<<(128 * 128 + 255) / 256, 256, 0, stream>>>(W0, W1, W2, Wt0, Wt1, Wt2);

  hipMemsetAsync(cursor, 0, (size_t)n * sizeof(int), stream);
  count_win_k<<<gwin, 256, 0, stream>>>(dstIdx, cursor, e, winSize);
  block_sum_k<<<nb, 256, 0, stream>>>(cursor, blockSums, n);
  scan_sums_k<<<1, 256, 0, stream>>>(blockSums, nb, row_ptr + n);
  scan_apply_k<<<nb, 256, 0, stream>>>(cursor, blockSums, row_ptr, n);
  scatter_win_k<<<gwin, 256, 0, stream>>>(srcIdx, dstIdx, cursor, csr, e, winSize);

  const int gb = (n + 63) / 64;
  const int gp = (n + 7) / 8;  // pair kernels: 8 nodes/block (4 waves x 2)

  // layer 0 (fp32 input -> conversion fused into staging)
  gemm_attn_mfma_k<128, 2, true><<<gb, 256, 0, stream>>>(x, Wt0, as0, ad0, xlh, sArr, dArr, n);
  edge2h_k<<<gp, 256, 0, stream>>>(xlh, sArr, dArr, b0, row_ptr, csr, bufHh, n);

  // layer 1
  gemm_attn_mfma_k<128, 2, false><<<gb, 256, 0, stream>>>(bufHh, Wt1, as1, ad1, xlh, sArr, dArr, n);
  edge2h_k<<<gp, 256, 0, stream>>>(xlh, sArr, dArr, b1, row_ptr, csr, bufHh, n);

  // layer 2 (H=1, no concat, no elu, fp32 out)
  gemm_attn_mfma_k<64, 1, false><<<gb, 256, 0, stream>>>(bufHh, Wt2, as2, ad2, xlh, sArr, dArr, n);
  edge1h_k<<<gp, 256, 0, stream>>>(xlh, sArr, dArr, b2, row_ptr, csr, out, n);
}

// Round 15
// 313.757 us; speedup vs baseline: 1.0542x; 1.0080x over previous
//
#include <hip/hip_runtime.h>
#include <hip/hip_fp16.h>
#include <math.h>

#define NEG_SLOPE 0.2f

__device__ __forceinline__ float lrelu(float v) { return v > 0.0f ? v : NEG_SLOPE * v; }

typedef _Float16 half8 __attribute__((ext_vector_type(8)));
typedef float floatx4 __attribute__((ext_vector_type(4)));

// ---------------- CSR build ----------------

// XCD-windowed count (windows disjoint; correctness independent of XCD mapping).
__global__ __launch_bounds__(256) void count_win_k(const int* __restrict__ dst,
                                                   int* __restrict__ counts,
                                                   int e, int winSize) {
  const int win = blockIdx.x & 7;
  const int lo = win * winSize;
  const int hi = lo + winSize;
  const int base = (blockIdx.x >> 3) * 4096 + threadIdx.x;
  for (int t = 0; t < 16; ++t) {
    int i = base + t * 256;
    if (i < e) {
      int d = dst[i];
      if (d >= lo && d < hi) atomicAdd(&counts[d], 1);
    }
  }
}

__global__ __launch_bounds__(256) void block_sum_k(const int* __restrict__ counts,
                                                   int* __restrict__ blockSums, int n) {
  int i = blockIdx.x * 256 + threadIdx.x;
  int v = (i < n) ? counts[i] : 0;
  for (int o = 32; o > 0; o >>= 1) v += __shfl_xor(v, o);
  __shared__ int ws[4];
  if ((threadIdx.x & 63) == 0) ws[threadIdx.x >> 6] = v;
  __syncthreads();
  if (threadIdx.x == 0) blockSums[blockIdx.x] = ws[0] + ws[1] + ws[2] + ws[3];
}

__global__ __launch_bounds__(256) void scan_sums_k(int* __restrict__ blockSums, int nb,
                                                   int* __restrict__ total_out) {
  __shared__ int sh[256];
  const int tid = threadIdx.x;
  int run = 0;
  for (int base = 0; base < nb; base += 256) {
    int i = base + tid;
    int v = (i < nb) ? blockSums[i] : 0;
    sh[tid] = v;
    __syncthreads();
    for (int o = 1; o < 256; o <<= 1) {
      int t = (tid >= o) ? sh[tid - o] : 0;
      __syncthreads();
      sh[tid] += t;
      __syncthreads();
    }
    int chunkTotal = sh[255];
    if (i < nb) blockSums[i] = run + sh[tid] - v;
    __syncthreads();
    run += chunkTotal;
  }
  if (tid == 0) *total_out = run;
}

__global__ __launch_bounds__(256) void scan_apply_k(int* __restrict__ counts_cursor,
                                                    const int* __restrict__ blockOffs,
                                                    int* __restrict__ row_ptr, int n) {
  __shared__ int sh[256];
  const int tid = threadIdx.x;
  const int i = blockIdx.x * 256 + tid;
  int v = (i < n) ? counts_cursor[i] : 0;
  sh[tid] = v;
  __syncthreads();
  for (int o = 1; o < 256; o <<= 1) {
    int t = (tid >= o) ? sh[tid - o] : 0;
    __syncthreads();
    sh[tid] += t;
    __syncthreads();
  }
  if (i < n) {
    int excl = blockOffs[blockIdx.x] + sh[tid] - v;
    row_ptr[i] = excl;
    counts_cursor[i] = excl;
  }
}

__global__ __launch_bounds__(256) void scatter_win_k(const int* __restrict__ src,
                                                     const int* __restrict__ dst,
                                                     int* __restrict__ cursor,
                                                     int* __restrict__ csr,
                                                     int e, int winSize) {
  const int win = blockIdx.x & 7;
  const int lo = win * winSize;
  const int hi = lo + winSize;
  const int base = (blockIdx.x >> 3) * 4096 + threadIdx.x;
  for (int t = 0; t < 16; ++t) {
    int i = base + t * 256;
    if (i < e) {
      int d = dst[i];
      if (d >= lo && d < hi) {
        int pos = atomicAdd(&cursor[d], 1);
        csr[pos] = src[i];
      }
    }
  }
}

// ---------------- weight converts (once per launch) ----------------

__global__ __launch_bounds__(256) void cvt_wt3_k(const float* __restrict__ W0,
                                                 const float* __restrict__ W1,
                                                 const float* __restrict__ W2,
                                                 __half* __restrict__ Wt0,
                                                 __half* __restrict__ Wt1,
                                                 __half* __restrict__ Wt2) {
  int i = blockIdx.x * 256 + threadIdx.x;
  if (i < 128 * 128) {
    int col = i >> 7, k = i & 127;
    Wt0[i] = __float2half(W0[k * 128 + col]);
    Wt1[i] = __float2half(W1[k * 128 + col]);
    if (col < 64) Wt2[(size_t)col * 128 + k] = __float2half(W2[k * 64 + col]);
  }
}

// ---------------- MFMA GEMM + fused attention dots ----------------

template<int M, int H_, bool IN_F32>
__global__ __launch_bounds__(256) void gemm_attn_mfma_k(const void* __restrict__ Xin,
                                                        const __half* __restrict__ Wt,
                                                        const float* __restrict__ a_src,
                                                        const float* __restrict__ a_dst,
                                                        __half* __restrict__ Yh,
                                                        float* __restrict__ sArr,
                                                        float* __restrict__ dArr, int n) {
  constexpr int CT = M / 16;
  constexpr int LP = 136;  // LDS row pitch in halves (272B: 2-way conflict = free)
  __shared__ _Float16 Xs[64 * LP];
  __shared__ _Float16 Ws[M * LP];
  const int tid = threadIdx.x;
  const int w = tid >> 6;
  const int lane = tid & 63;
  const int l15 = lane & 15;
  const int quad = lane >> 4;
  const int rb = blockIdx.x * 64;

  if (IN_F32) {
    const float* Xf = (const float*)Xin;
    for (int t = 0; t < 8; ++t) {
      int idx = tid + t * 256;
      int r = idx >> 5, c4 = idx & 31;
      float4 v = make_float4(0.f, 0.f, 0.f, 0.f);
      if (rb + r < n) v = *(const float4*)(Xf + (size_t)(rb + r) * 128 + c4 * 4);
      __half2 a = __floats2half2_rn(v.x, v.y);
      __half2 b = __floats2half2_rn(v.z, v.w);
      uint2 pk;
      pk.x = *(unsigned int*)&a;
      pk.y = *(unsigned int*)&b;
      *(uint2*)&Xs[r * LP + c4 * 4] = pk;
    }
  } else {
    const __half* Xh = (const __half*)Xin;
    for (int t = 0; t < 4; ++t) {
      int idx = tid + t * 256;
      int r = idx >> 4, c8 = idx & 15;
      uint4 v = make_uint4(0, 0, 0, 0);
      if (rb + r < n) v = *(const uint4*)(Xh + (size_t)(rb + r) * 128 + c8 * 8);
      *(uint4*)&Xs[r * LP + c8 * 8] = v;
    }
  }
  for (int t = 0; t < CT; ++t) {
    int idx = tid + t * 256;
    int r = idx >> 4, c8 = idx & 15;
    *(uint4*)&Ws[r * LP + c8 * 8] = *(const uint4*)(Wt + (size_t)r * 128 + c8 * 8);
  }
  __syncthreads();

  floatx4 acc[CT];
  for (int c = 0; c < CT; ++c)
    for (int j = 0; j < 4; ++j) acc[c][j] = 0.f;

  const int arow = w * 16 + l15;
  for (int kq = 0; kq < 4; ++kq) {
    half8 a = *(const half8*)&Xs[arow * LP + kq * 32 + quad * 8];
    for (int c = 0; c < CT; ++c) {
      half8 b = *(const half8*)&Ws[(c * 16 + l15) * LP + kq * 32 + quad * 8];
      acc[c] = __builtin_amdgcn_mfma_f32_16x16x32_f16(a, b, acc[c], 0, 0, 0);
    }
  }

  float as[CT], ad[CT];
  for (int c = 0; c < CT; ++c) {
    as[c] = a_src[c * 16 + l15];
    ad[c] = a_dst[c * 16 + l15];
  }

  for (int c = 0; c < CT; ++c) {
    for (int r = 0; r < 4; ++r) {
      int row = rb + w * 16 + quad * 4 + r;
      if (row < n) Yh[(size_t)row * M + c * 16 + l15] = __float2half(acc[c][r]);
    }
  }

  for (int r = 0; r < 4; ++r) {
    int row = rb + w * 16 + quad * 4 + r;
    float s0 = 0.f, d0 = 0.f, s1 = 0.f, d1 = 0.f;
    if (H_ == 2) {
      for (int c = 0; c < CT / 2; ++c) {
        s0 += acc[c][r] * as[c];
        d0 += acc[c][r] * ad[c];
      }
      for (int c = CT / 2; c < CT; ++c) {
        s1 += acc[c][r] * as[c];
        d1 += acc[c][r] * ad[c];
      }
    } else {
      for (int c = 0; c < CT; ++c) {
        s0 += acc[c][r] * as[c];
        d0 += acc[c][r] * ad[c];
      }
    }
    for (int o = 1; o < 16; o <<= 1) {
      s0 += __shfl_xor(s0, o);
      d0 += __shfl_xor(d0, o);
      if (H_ == 2) {
        s1 += __shfl_xor(s1, o);
        d1 += __shfl_xor(d1, o);
      }
    }
    if (l15 == 0 && row < n) {
      if (H_ == 2) {
        sArr[row * 2] = s0;
        sArr[row * 2 + 1] = s1;
        dArr[row * 2] = d0;
        dArr[row * 2 + 1] = d1;
      } else {
        sArr[row] = s0;
        dArr[row] = d0;
      }
    }
  }
}

// ---------------- aggregation: FOUR nodes per wave, 16 lanes each, unroll 4 ---------
// fp16 H=2 row = 256 B = 16 lanes x uint4(16B): quarter-wave covers a full row,
// so every loop instruction serves 4 edges. Degree mismatch across the quad is
// handled by the exec mask. Per-lane den sums its own node+head's weights over
// all its node's edges = that head's denominator. Lane l16 covers halves
// [l16*8, l16*8+8) -> head = l16>>3.

__global__ __launch_bounds__(256) void edge2h_k(const __half* __restrict__ xlh,
                                                const float* __restrict__ sArr,
                                                const float* __restrict__ dArr,
                                                const float* __restrict__ bias,
                                                const int* __restrict__ row_ptr,
                                                const int* __restrict__ csr,
                                                __half* __restrict__ outh, int n) {
  const int wid = threadIdx.x >> 6;
  const int lane = threadIdx.x & 63;
  const int sub = lane >> 4;            // which node of the quad
  const int l16 = lane & 15;            // 16B unit within the 256B row
  const int node = blockIdx.x * 16 + wid * 4 + sub;
  if (node >= n) return;
  const int row = row_ptr[node];
  const int deg = row_ptr[node + 1] - row;
  const int head = l16 >> 3;
  const uint4* __restrict__ xq = (const uint4*)xlh;   // row stride 16 units
  const float dnsel = dArr[node * 2 + head];

  // self-loop loads early (overlap with first edge batch)
  float svS = sArr[node * 2 + head];
  uint4 pS = xq[(size_t)node * 16 + l16];

  float a0 = 0.f, a1 = 0.f, a2 = 0.f, a3 = 0.f;
  float a4 = 0.f, a5 = 0.f, a6 = 0.f, a7 = 0.f;
  float den = 0.f;
  int j = 0;
  for (; j + 4 <= deg; j += 4) {
    int idx[4];
    float sv[4];
    uint4 p[4];
    for (int t = 0; t < 4; ++t) idx[t] = csr[row + j + t];
    for (int t = 0; t < 4; ++t) sv[t] = sArr[idx[t] * 2 + head];
    for (int t = 0; t < 4; ++t) p[t] = xq[(size_t)idx[t] * 16 + l16];
    for (int t = 0; t < 4; ++t) {
      float w = __expf(lrelu(sv[t] + dnsel));
      den += w;
      float2 v0 = __half22float2(*(__half2*)&p[t].x);
      float2 v1 = __half22float2(*(__half2*)&p[t].y);
      float2 v2 = __half22float2(*(__half2*)&p[t].z);
      float2 v3 = __half22float2(*(__half2*)&p[t].w);
      a0 += w * v0.x; a1 += w * v0.y; a2 += w * v1.x; a3 += w * v1.y;
      a4 += w * v2.x; a5 += w * v2.y; a6 += w * v3.x; a7 += w * v3.y;
    }
  }
  for (; j < deg; ++j) {
    int i0 = csr[row + j];
    float sv = sArr[i0 * 2 + head];
    uint4 p = xq[(size_t)i0 * 16 + l16];
    float w = __expf(lrelu(sv + dnsel));
    den += w;
    float2 v0 = __half22float2(*(__half2*)&p.x);
    float2 v1 = __half22float2(*(__half2*)&p.y);
    float2 v2 = __half22float2(*(__half2*)&p.z);
    float2 v3 = __half22float2(*(__half2*)&p.w);
    a0 += w * v0.x; a1 += w * v0.y; a2 += w * v1.x; a3 += w * v1.y;
    a4 += w * v2.x; a5 += w * v2.y; a6 += w * v3.x; a7 += w * v3.y;
  }
  // self loop
  float wS = __expf(lrelu(svS + dnsel));
  den += wS;
  {
    float2 v0 = __half22float2(*(__half2*)&pS.x);
    float2 v1 = __half22float2(*(__half2*)&pS.y);
    float2 v2 = __half22float2(*(__half2*)&pS.z);
    float2 v3 = __half22float2(*(__half2*)&pS.w);
    a0 += wS * v0.x; a1 += wS * v0.y; a2 += wS * v1.x; a3 += wS * v1.y;
    a4 += wS * v2.x; a5 += wS * v2.y; a6 += wS * v3.x; a7 += wS * v3.y;
  }

  float wi = 1.f / den;
  float4 bbA = ((const float4*)bias)[l16 * 2];
  float4 bbB = ((const float4*)bias)[l16 * 2 + 1];
  float r0 = a0 * wi + bbA.x;
  float r1 = a1 * wi + bbA.y;
  float r2 = a2 * wi + bbA.z;
  float r3 = a3 * wi + bbA.w;
  float r4 = a4 * wi + bbB.x;
  float r5 = a5 * wi + bbB.y;
  float r6 = a6 * wi + bbB.z;
  float r7 = a7 * wi + bbB.w;
  r0 = r0 > 0.f ? r0 : expm1f(r0);
  r1 = r1 > 0.f ? r1 : expm1f(r1);
  r2 = r2 > 0.f ? r2 : expm1f(r2);
  r3 = r3 > 0.f ? r3 : expm1f(r3);
  r4 = r4 > 0.f ? r4 : expm1f(r4);
  r5 = r5 > 0.f ? r5 : expm1f(r5);
  r6 = r6 > 0.f ? r6 : expm1f(r6);
  r7 = r7 > 0.f ? r7 : expm1f(r7);
  __half2 h0 = __floats2half2_rn(r0, r1);
  __half2 h1 = __floats2half2_rn(r2, r3);
  __half2 h2 = __floats2half2_rn(r4, r5);
  __half2 h3 = __floats2half2_rn(r6, r7);
  uint4 pk;
  pk.x = *(unsigned int*)&h0;
  pk.y = *(unsigned int*)&h1;
  pk.z = *(unsigned int*)&h2;
  pk.w = *(unsigned int*)&h3;
  ((uint4*)outh)[(size_t)node * 16 + l16] = pk;
}

// H=1: row = 64 halves = 128 B = 16 lanes x uint2(8B); fp32 out (float4/lane).
__global__ __launch_bounds__(256) void edge1h_k(const __half* __restrict__ xlh,
                                                const float* __restrict__ sArr,
                                                const float* __restrict__ dArr,
                                                const float* __restrict__ bias,
                                                const int* __restrict__ row_ptr,
                                                const int* __restrict__ csr,
                                                float* __restrict__ outp, int n) {
  const int wid = threadIdx.x >> 6;
  const int lane = threadIdx.x & 63;
  const int sub = lane >> 4;
  const int l16 = lane & 15;
  const int node = blockIdx.x * 16 + wid * 4 + sub;
  if (node >= n) return;
  const int row = row_ptr[node];
  const int deg = row_ptr[node + 1] - row;
  const uint2* __restrict__ xq = (const uint2*)xlh;   // 8B units, row stride 16
  const float dn = dArr[node];

  float svS = sArr[node];
  uint2 pS = xq[(size_t)node * 16 + l16];

  float a0 = 0.f, a1 = 0.f, a2 = 0.f, a3 = 0.f;
  float den = 0.f;
  int j = 0;
  for (; j + 4 <= deg; j += 4) {
    int idx[4];
    float sv[4];
    uint2 p[4];
    for (int t = 0; t < 4; ++t) idx[t] = csr[row + j + t];
    for (int t = 0; t < 4; ++t) sv[t] = sArr[idx[t]];
    for (int t = 0; t < 4; ++t) p[t] = xq[(size_t)idx[t] * 16 + l16];
    for (int t = 0; t < 4; ++t) {
      float w = __expf(lrelu(sv[t] + dn));
      den += w;
      float2 v0 = __half22float2(*(__half2*)&p[t].x);
      float2 v1 = __half22float2(*(__half2*)&p[t].y);
      a0 += w * v0.x; a1 += w * v0.y; a2 += w * v1.x; a3 += w * v1.y;
    }
  }
  for (; j < deg; ++j) {
    int i0 = csr[row + j];
    float sv = sArr[i0];
    uint2 p = xq[(size_t)i0 * 16 + l16];
    float w = __expf(lrelu(sv + dn));
    den += w;
    float2 v0 = __half22float2(*(__half2*)&p.x);
    float2 v1 = __half22float2(*(__half2*)&p.y);
    a0 += w * v0.x; a1 += w * v0.y; a2 += w * v1.x; a3 += w * v1.y;
  }
  float wS = __expf(lrelu(svS + dn));
  den += wS;
  {
    float2 v0 = __half22float2(*(__half2*)&pS.x);
    float2 v1 = __half22float2(*(__half2*)&pS.y);
    a0 += wS * v0.x; a1 += wS * v0.y; a2 += wS * v1.x; a3 += wS * v1.y;
  }

  float wi = 1.f / den;
  float4 bb = ((const float4*)bias)[l16];
  float4 r;
  r.x = a0 * wi + bb.x;
  r.y = a1 * wi + bb.y;
  r.z = a2 * wi + bb.z;
  r.w = a3 * wi + bb.w;
  ((float4*)outp)[(size_t)node * 16 + l16] = r;
}

// ---------------- launch ----------------

extern "C" void kernel_launch(void* const* d_in, const int* in_sizes, int n_in,
                              void* d_out, int out_size, void* d_ws, size_t ws_size,
                              hipStream_t stream) {
  const float* x  = (const float*)d_in[0];
  const int* ei   = (const int*)d_in[1];
  const float* W0 = (const float*)d_in[2];
  const float* as0 = (const float*)d_in[3];
  const float* ad0 = (const float*)d_in[4];
  const float* b0 = (const float*)d_in[5];
  const float* W1 = (const float*)d_in[6];
  const float* as1 = (const float*)d_in[7];
  const float* ad1 = (const float*)d_in[8];
  const float* b1 = (const float*)d_in[9];
  const float* W2 = (const float*)d_in[10];
  const float* as2 = (const float*)d_in[11];
  const float* ad2 = (const float*)d_in[12];
  const float* b2 = (const float*)d_in[13];
  float* out = (float*)d_out;

  const int n = in_sizes[0] / 128;
  const int e = in_sizes[1] / 2;
  const int* srcIdx = ei;
  const int* dstIdx = ei + e;

  float* ws = (float*)d_ws;
  float* sArr = ws;                                  // n*2
  float* dArr = sArr + (size_t)n * 2;                // n*2
  __half* xlh = (__half*)(dArr + (size_t)n * 2);     // n*128 halves
  __half* bufHh = xlh + (size_t)n * 128;             // n*128 halves
  __half* Wt0 = bufHh + (size_t)n * 128;             // 128*128
  __half* Wt1 = Wt0 + 128 * 128;                     // 128*128
  __half* Wt2 = Wt1 + 128 * 128;                     // 64*128
  int* csr = (int*)(Wt2 + 64 * 128);                 // e
  int* row_ptr = csr + e;                            // n+1
  int* cursor = row_ptr + (n + 1);                   // n
  int* blockSums = cursor + n;                       // nb

  const int nb = (n + 255) / 256;
  const int winSize = (n + 7) / 8;
  const int gwin = 8 * ((e + 4095) / 4096);

  cvt_wt3_k<<<(128 * 128 + 255) / 256, 256, 0, stream>>>(W0, W1, W2, Wt0, Wt1, Wt2);

  hipMemsetAsync(cursor, 0, (size_t)n * sizeof(int), stream);
  count_win_k<<<gwin, 256, 0, stream>>>(dstIdx, cursor, e, winSize);
  block_sum_k<<<nb, 256, 0, stream>>>(cursor, blockSums, n);
  scan_sums_k<<<1, 256, 0, stream>>>(blockSums, nb, row_ptr + n);
  scan_apply_k<<<nb, 256, 0, stream>>>(cursor, blockSums, row_ptr, n);
  scatter_win_k<<<gwin, 256, 0, stream>>>(srcIdx, dstIdx, cursor, csr, e, winSize);

  const int gb = (n + 63) / 64;
  const int gq = (n + 15) / 16;  // quad kernels: 16 nodes/block (4 waves x 4)

  // layer 0 (fp32 input -> conversion fused into staging)
  gemm_attn_mfma_k<128, 2, true><<<gb, 256, 0, stream>>>(x, Wt0, as0, ad0, xlh, sArr, dArr, n);
  edge2h_k<<<gq, 256, 0, stream>>>(xlh, sArr, dArr, b0, row_ptr, csr, bufHh, n);

  // layer 1
  gemm_attn_mfma_k<128, 2, false><<<gb, 256, 0, stream>>>(bufHh, Wt1, as1, ad1, xlh, sArr, dArr, n);
  edge2h_k<<<gq, 256, 0, stream>>>(xlh, sArr, dArr, b1, row_ptr, csr, bufHh, n);

  // layer 2 (H=1, no concat, no elu, fp32 out)
  gemm_attn_mfma_k<64, 1, false><<<gb, 256, 0, stream>>>(bufHh, Wt2, as2, ad2, xlh, sArr, dArr, n);
  edge1h_k<<<gq, 256, 0, stream>>>(xlh, sArr, dArr, b2, row_ptr, csr, out, n);
}